// Round 21
// baseline (38.731 us; speedup 1.0000x reference)
//
#include <hip/hip_runtime.h>
#include <hip/hip_bf16.h>

// N=8192 points, k=8 kNN -> mean |plane distance|.
// R21: threshold computed INSIDE mfma_knn from an MFMA pre-pass stage (1024
// cols) -- the separate sampling/threshold kernel (latency-bound straggler) is
// reduced to a trivial pack. T = 8th-smallest of 32 per-lane mins + truncation
// margin; both mask and selection operate on the same MFMA accs, so no
// approx-error margin is needed. Selection = R20's acc-based keys (absmax 0).
//   d2(r,c) via 16x16x32 bf16 MFMA, hi/lo split over 13 K-slots (validated
//   R10-R20). Neighbor indices exact; plane distances exact f32.
#define NPTS 8192
#define KNN 8
#define RPB 16            // rows per block
#define STAGES 8
#define SCOLS 1024        // cols per stage; wave band = 128 cols = 8 MFMA

typedef __attribute__((ext_vector_type(8))) short bf16x8;
typedef __attribute__((ext_vector_type(4))) float f32x4;

__device__ __forceinline__ unsigned int bf16rne(float v) {
    unsigned int u = __float_as_uint(v);
    return (u + 0x7FFFu + ((u >> 16) & 1u)) >> 16;
}
__device__ __forceinline__ float bf2f(unsigned int h) { return __uint_as_float(h << 16); }

__device__ __forceinline__ void insert8(unsigned int (&best)[KNN], unsigned int key) {
#pragma unroll
    for (int t = 0; t < KNN; ++t) {
        const unsigned int lo = min(best[t], key);
        key = max(best[t], key);
        best[t] = lo;
    }
}
__device__ __forceinline__ void finsert8(float (&b)[KNN], float key) {
#pragma unroll
    for (int t = 0; t < KNN; ++t) {
        const float lo = fminf(b[t], key);
        key = fmaxf(b[t], key);
        b[t] = lo;
    }
}

// Pure pack: pts + candidate frags + row frags; zero out. 8192 threads.
__global__ __launch_bounds__(256) void pack_kernel(const float* __restrict__ means,
                                                   float4* __restrict__ pts,
                                                   uint4* __restrict__ cf0,
                                                   uint4* __restrict__ cf1,
                                                   uint4* __restrict__ rf0,
                                                   uint4* __restrict__ rf1,
                                                   float* __restrict__ out) {
    const int i = blockIdx.x * 256 + threadIdx.x;
    if (i == 0) out[0] = 0.0f;
    const float x = means[3 * i + 0];
    const float y = means[3 * i + 1];
    const float z = means[3 * i + 2];
    const float sq = x * x + y * y + z * z;
    pts[i] = make_float4(x, y, z, sq);
    const unsigned int hx = bf16rne(x), lx = bf16rne(x - bf2f(hx));
    const unsigned int hy = bf16rne(y), ly = bf16rne(y - bf2f(hy));
    const unsigned int hz = bf16rne(z), lz = bf16rne(z - bf2f(hz));
    const unsigned int hs = bf16rne(sq), ls = bf16rne(sq - bf2f(hs));
    cf0[i] = make_uint4(hx | (lx << 16), hx | (hy << 16),
                        ly | (hy << 16), hz | (lz << 16));
    cf1[i] = make_uint4(hz | (hs << 16), ls | (0x3F80u << 16), 0x3F80u, 0u);
    const float ax = -2.0f * x, ay = -2.0f * y, az = -2.0f * z;
    const unsigned int hax = bf16rne(ax), lax = bf16rne(ax - bf2f(hax));
    const unsigned int hay = bf16rne(ay), lay = bf16rne(ay - bf2f(hay));
    const unsigned int haz = bf16rne(az), laz = bf16rne(az - bf2f(haz));
    const unsigned int hsr = bf16rne(sq), lsr = bf16rne(sq - bf2f(hsr));
    rf0[i] = make_uint4(hax | (hax << 16), lax | (hay << 16),
                        hay | (lay << 16), haz | (haz << 16));
    rf1[i] = make_uint4(laz | (0x3F80u << 16), 0x3F80u | (hsr << 16), lsr, 0u);
}

// 512 blocks x 512 threads (8 waves); block owns 16 rows.
// Pre-pass on stage sp (!= own-row window): lane-min -> per-row 8th-smallest
// -> T. Main loop: 8 stages, mask acc<=T, LDS-acc decode, insert8.
__global__ __launch_bounds__(512) void mfma_knn(const uint4* __restrict__ cf0,
                                                const uint4* __restrict__ cf1,
                                                const uint4* __restrict__ rf0,
                                                const uint4* __restrict__ rf1,
                                                const float4* __restrict__ pts,
                                                const float* __restrict__ normals,
                                                float* __restrict__ out) {
    __shared__ unsigned int lds_acc[8][16][64];   // 32 KB; [wave][t][lane]
    __shared__ float lds_min[16][33];             // lane-mins (+pad)
    __shared__ float lds_T[16];
    __shared__ unsigned int km[8][RPB][KNN + 1];
    const int tid = threadIdx.x;
    const int l = tid & 63;
    const int wv = __builtin_amdgcn_readfirstlane(tid >> 6);
    const int R = l & 15;     // my query row
    const int g = l >> 4;     // candidate sub-slice
    const int arow = blockIdx.x * RPB + R;

    const float4 mp = pts[arow];

    // B fragment: my row; lanes g>=2 supply zero (their K-slots unused)
    uint4 bu = make_uint4(0u, 0u, 0u, 0u);
    if (g == 0) bu = rf0[arow];
    else if (g == 1) bu = rf1[arow];
    union { uint4 u; bf16x8 v; } Bf; Bf.u = bu;
    const f32x4 zero = {0.0f, 0.0f, 0.0f, 0.0f};

    // A-fragments from L2; g>=2 lanes duplicate g0's address (broadcast, free)
    const uint4* __restrict__ asel = (g == 1) ? cf1 : cf0;

    // ---- pre-pass: stage sp (own rows excluded by construction) ----
    const int sp = (((int)blockIdx.x >> 6) + 1) & 7;
    {
        const int lbase = sp * SCOLS + wv * 128 + R;
        float lmin = 3.4e38f;
#pragma unroll
        for (int mt = 0; mt < 8; ++mt) {
            union { uint4 u; bf16x8 v; } Af;
            Af.u = asel[lbase + mt * 16];
            const f32x4 acc = __builtin_amdgcn_mfma_f32_16x16x32_bf16(Af.v, Bf.v, zero, 0, 0, 0);
            lmin = fminf(lmin, fminf(fminf(acc[0], acc[1]), fminf(acc[2], acc[3])));
        }
        lds_min[R][wv * 4 + g] = lmin;
    }
    __syncthreads();
    {   // per-row 8th-smallest of 32 lane-mins; wave wv owns rows 2wv, 2wv+1
        const int row = wv * 2 + (l >> 5);
        float bb[KNN];
        bb[0] = lds_min[row][l & 31];
#pragma unroll
        for (int s = 1; s < KNN; ++s) bb[s] = 3.4e38f;
#pragma unroll
        for (int st = 1; st <= 16; st <<= 1) {
            float tk[KNN];
#pragma unroll
            for (int s = 0; s < KNN; ++s) tk[s] = __shfl_xor(bb[s], st);
#pragma unroll
            for (int s = 0; s < KNN; ++s) finsert8(bb, tk[s]);
        }
        if ((l & 31) == 0)
            lds_T[row] = bb[7] + 0.002f * fabsf(bb[7]) + 1e-5f;  // truncation margin
    }
    __syncthreads();
    const float Tm = lds_T[R];

    unsigned int best[KNN];
#pragma unroll
    for (int s = 0; s < KNN; ++s) best[s] = ~0u;

    // ---- main loop: 8 stages x (2 half-stages: 4 MFMA, spill, mask, decode)
#pragma unroll 1
    for (int s = 0; s < STAGES; ++s) {
        const int lbase = s * SCOLS + wv * 128 + R;
        const int cbase = s * SCOLS + wv * 128;
#pragma unroll
        for (int h = 0; h < 2; ++h) {
            unsigned int m = 0u;
#pragma unroll
            for (int mt4 = 0; mt4 < 4; ++mt4) {
                const int mt = h * 4 + mt4;
                union { uint4 u; bf16x8 v; } Af;
                Af.u = asel[lbase + mt * 16];
                const f32x4 acc = __builtin_amdgcn_mfma_f32_16x16x32_bf16(Af.v, Bf.v, zero, 0, 0, 0);
                lds_acc[wv][mt4 * 4 + 0][l] = __float_as_uint(acc[0]);
                lds_acc[wv][mt4 * 4 + 1][l] = __float_as_uint(acc[1]);
                lds_acc[wv][mt4 * 4 + 2][l] = __float_as_uint(acc[2]);
                lds_acc[wv][mt4 * 4 + 3][l] = __float_as_uint(acc[3]);
                m = m + m + ((acc[0] <= Tm) ? 1u : 0u);
                m = m + m + ((acc[1] <= Tm) ? 1u : 0u);
                m = m + m + ((acc[2] <= Tm) ? 1u : 0u);
                m = m + m + ((acc[3] <= Tm) ? 1u : 0u);
            }
            // decode survivors: acc from LDS (own-wave data; program order ok)
            while (m) {
                const int b = __ffs(m) - 1;
                m &= m - 1;
                const int t = 15 - b;                 // t = mt4*4 + r
                const float av = fmaxf(__uint_as_float(lds_acc[wv][t][l]), 0.0f);
                const int col = cbase + (h * 4 + (t >> 2)) * 16 + g * 4 + (t & 3);
                unsigned int key = (__float_as_uint(av) & 0xFFFFE000u) | (unsigned int)col;
                key = (col == arow) ? ~0u : key;      // drop self
                insert8(best, key);
            }
        }
    }

    // merge the 4 g-lanes sharing this row within the wave
#pragma unroll
    for (int st = 16; st <= 32; st <<= 1) {
        unsigned int tk[KNN];
#pragma unroll
        for (int s = 0; s < KNN; ++s) tk[s] = __shfl_xor(best[s], st);
#pragma unroll
        for (int s = 0; s < KNN; ++s) insert8(best, tk[s]);
    }
    // merge across 8 waves (LDS tree)
    if (l < RPB) {
#pragma unroll
        for (int s = 0; s < KNN; ++s) km[wv][l][s] = best[s];
    }
    for (int st = 1; st < 8; st <<= 1) {
        __syncthreads();
        if (((wv & (2 * st - 1)) == 0) && l < RPB) {
#pragma unroll
            for (int s = 0; s < KNN; ++s) insert8(best, km[wv + st][l][s]);
#pragma unroll
            for (int s = 0; s < KNN; ++s) km[wv][l][s] = best[s];
        }
    }

    // finalize: wave 0, lanes 0..15 hold the 16 rows (indices exact)
    if (wv == 0) {
        float sum = 0.0f;
        if (l < RPB) {
            const float nx = normals[3 * arow + 0];
            const float ny = normals[3 * arow + 1];
            const float nz = normals[3 * arow + 2];
#pragma unroll
            for (int s = 0; s < KNN; ++s) {
                const int nbr = (int)(best[s] & 0x1FFFu);
                const float4 q = pts[nbr];
                sum += fabsf((q.x - mp.x) * nx + (q.y - mp.y) * ny + (q.z - mp.z) * nz);
            }
        }
#pragma unroll
        for (int off = 8; off > 0; off >>= 1) sum += __shfl_down(sum, off);
        if (l == 0) atomicAdd(out, sum * (1.0f / ((float)NPTS * (float)KNN)));
    }
}

extern "C" void kernel_launch(void* const* d_in, const int* in_sizes, int n_in,
                              void* d_out, int out_size, void* d_ws, size_t ws_size,
                              hipStream_t stream) {
    const float* means = (const float*)d_in[0];
    const float* normals = (const float*)d_in[1];
    float* out = (float*)d_out;
    char* ws = (char*)d_ws;
    uint4* cf0 = (uint4*)ws;                        // 128 KB
    uint4* cf1 = (uint4*)(ws + 131072);             // 128 KB
    uint4* rf0 = (uint4*)(ws + 262144);             // 128 KB
    uint4* rf1 = (uint4*)(ws + 393216);             // 128 KB
    float4* pts = (float4*)(ws + 524288);           // 128 KB

    pack_kernel<<<NPTS / 256, 256, 0, stream>>>(means, pts, cf0, cf1, rf0, rf1, out);
    mfma_knn<<<NPTS / RPB, 512, 0, stream>>>(cf0, cf1, rf0, rf1, pts, normals, out);
}